// Round 10
// baseline (610.357 us; speedup 1.0000x reference)
//
#include <hip/hip_runtime.h>
#include <math.h>

#define DEVI __device__ __forceinline__

namespace {

constexpr int N_  = 2048;
constexpr int E_  = 32768;
constexpr int E2_ = 65536;
constexpr int M_  = 64000;   // 8 * 20^3
constexpr int NT_ = 2048;    // radial table resolution
constexpr float TMAX_ = 5.5f;
constexpr float TH_ = TMAX_ / NT_;

DEVI float sigm(float x)  { return 1.0f/(1.0f+expf(-x)); }
DEVI float geluf(float x) {
  float t = tanhf(0.7978845608028654f*(x + 0.044715f*x*x*x));
  return 0.5f*x*(1.0f+t);
}

// ---------------- utility ----------------
__global__ void zero_k(float* __restrict__ p, int n){
  int i = blockIdx.x*256 + threadIdx.x;
  if (i < n) p[i] = 0.0f;
}

__global__ void meshpos_k(const float* __restrict__ cell, float* __restrict__ mp){
  int m = blockIdx.x*256 + threadIdx.x;
  if (m >= M_) return;
  int b = m/8000, r = m%8000;
  float fx = (float)(r/400)    * 0.05f;
  float fy = (float)((r/20)%20)* 0.05f;
  float fz = (float)(r%20)     * 0.05f;
  const float* c = cell + b*9;
  mp[(size_t)m*3+0] = fx*c[0] + fy*c[3] + fz*c[6];
  mp[(size_t)m*3+1] = fx*c[1] + fy*c[4] + fz*c[7];
  mp[(size_t)m*3+2] = fx*c[2] + fy*c[5] + fz*c[8];
}

// edge geometry: ev = P[pi[e]] - Q[qi[e]]; writes sh (9) and el (1)
__global__ void edge_geom2_k(const float* __restrict__ Ppos, const int* __restrict__ pi,
                             const float* __restrict__ Qpos, const int* __restrict__ qi,
                             float* __restrict__ sh, float* __restrict__ el_out, int nE){
  int e = blockIdx.x*256 + threadIdx.x;
  if (e >= nE) return;
  int a = pi[e], b = qi[e];
  float ex = Ppos[(size_t)a*3+0] - Qpos[(size_t)b*3+0];
  float ey = Ppos[(size_t)a*3+1] - Qpos[(size_t)b*3+1];
  float ez = Ppos[(size_t)a*3+2] - Qpos[(size_t)b*3+2];
  float el = sqrtf(ex*ex+ey*ey+ez*ez) + 1e-8f;
  el_out[e] = el;
  float x = ex/el, y = ey/el, z = ez/el;
  float* s = sh + (size_t)e*9;
  s[0] = 0.28209479177387814f;
  s[1] = 0.4886025119029199f*y;
  s[2] = 0.4886025119029199f*z;
  s[3] = 0.4886025119029199f*x;
  s[4] = 1.0925484305920792f*x*y;
  s[5] = 1.0925484305920792f*y*z;
  s[6] = 0.31539156525252005f*(3.0f*z*z-1.0f);
  s[7] = 1.0925484305920792f*x*z;
  s[8] = 0.5462742152960396f*(x*x-y*y);
}

__global__ void gather_emb_k(const float* __restrict__ emb, const int* __restrict__ an,
                             float* __restrict__ x16){
  int idx = blockIdx.x*256 + threadIdx.x;
  if (idx >= N_*16) return;
  int n = idx >> 4, f = idx & 15;
  x16[idx] = emb[(size_t)an[n]*16 + f];
}

// ---------------- radial tables ----------------
__global__ void es_k(float* __restrict__ Es){
  int idx = blockIdx.x*256 + threadIdx.x;
  if (idx >= NT_*64) return;
  int r = idx >> 6, k = idx & 63;
  const float step = 5.0f/63.0f;
  float d = (r*TH_ - k*step)/step;
  Es[idx] = expf(-d*d)*(8.0f/1.12f);
}

DEVI float lerp_tab(const float* __restrict__ T, float el, int O, int o){
  float u = el * (1.0f/TH_);
  u = fminf(u, (float)(NT_-1));
  int i = (int)u; if (i > NT_-2) i = NT_-2;
  float f = u - (float)i;
  float t0 = T[(size_t)i*O + o];
  float t1 = T[(size_t)(i+1)*O + o];
  return t0 + f*(t1 - t0);
}

// ---------------- tiled GEMMs ----------------
// batched table GEMM: 64x64 tile, 4x4/thread, float4 LDS reads
struct BG {
  const float* A[5]; const float* B[5]; float* C[5];
  int K; int Nc[5];
};
template<int ACT>
__global__ __launch_bounds__(256) void bgemm_k(BG args){
  int chain = blockIdx.z;
  const float* A = args.A[chain];
  const float* Bm = args.B[chain];
  float* C = args.C[chain];
  int K = args.K, Nc = args.Nc[chain];
  int row0 = blockIdx.y*64, col0 = blockIdx.x*64;
  if (col0 >= Nc) return;
  __shared__ float As[16][72];
  __shared__ float Bs[16][72];
  int tid = threadIdx.x;
  int tx = tid & 15, ty = tid >> 4;
  float acc[4][4] = {};
  for (int k0 = 0; k0 < K; k0 += 16) {
    { int kk = tid & 15; int mloc = tid >> 4;
      int gk = k0 + kk;
      #pragma unroll
      for (int p = 0; p < 4; ++p) {
        int m = mloc + p*16; int gm = row0 + m;
        As[kk][m] = A[(size_t)gm*K + gk];
      } }
    { int nn = tid & 63; int kl = tid >> 6;
      #pragma unroll
      for (int p = 0; p < 4; ++p) {
        int kk = kl + p*4; int gk = k0 + kk; int gn = col0 + nn;
        Bs[kk][nn] = (gn < Nc) ? Bm[(size_t)gk*Nc + gn] : 0.0f;
      } }
    __syncthreads();
    #pragma unroll
    for (int kk = 0; kk < 16; ++kk) {
      float4 a4 = *(const float4*)&As[kk][ty*4];
      float4 b4 = *(const float4*)&Bs[kk][tx*4];
      float a[4] = {a4.x,a4.y,a4.z,a4.w};
      float b[4] = {b4.x,b4.y,b4.z,b4.w};
      #pragma unroll
      for (int i=0;i<4;++i)
        #pragma unroll
        for (int j=0;j<4;++j) acc[i][j] += a[i]*b[j];
    }
    __syncthreads();
  }
  for (int i=0;i<4;++i) {
    int gm = row0 + ty*4+i;
    for (int j=0;j<4;++j) {
      int gn = col0 + tx*4+j; if (gn >= Nc) continue;
      float v = acc[i][j];
      if (ACT==1) v = v*sigm(v);
      C[(size_t)gm*Nc + gn] = v;
    }
  }
}

// general GEMM: 64x128 tile, 4x8/thread, float4 LDS reads. C = A@B
__global__ __launch_bounds__(256) void gemm128_k(const float* __restrict__ A, const float* __restrict__ B,
                        float* __restrict__ C, int Mr, int K, int Nc){
  __shared__ float As[16][72];
  __shared__ float Bs[16][136];
  int tid = threadIdx.x;
  int row0 = blockIdx.y*64, col0 = blockIdx.x*128;
  int tx = tid & 15, ty = tid >> 4;
  float acc[4][8] = {};
  for (int k0 = 0; k0 < K; k0 += 16) {
    { // A tile: 64x16, transposed into As[kk][m]
      int kk = tid & 15, mloc = tid >> 4;
      int gk = k0 + kk;
      #pragma unroll
      for (int p = 0; p < 4; ++p) {
        int m = mloc + p*16; int gm = row0 + m;
        As[kk][m] = (gm < Mr) ? A[(size_t)gm*K + gk] : 0.0f;
      }
    }
    { // B tile: 16x128, float4 loads
      int nn4 = tid & 31, kk = tid >> 5;
      #pragma unroll
      for (int p = 0; p < 2; ++p) {
        int kkk = kk + p*8;
        int gk = k0 + kkk;
        int gn = col0 + nn4*4;
        float4 v = make_float4(0.f,0.f,0.f,0.f);
        if (gn + 3 < Nc) {
          v = *(const float4*)(B + (size_t)gk*Nc + gn);
        } else if (gn < Nc) {
          float t0 = B[(size_t)gk*Nc + gn];
          float t1 = (gn+1<Nc)? B[(size_t)gk*Nc + gn+1] : 0.f;
          float t2 = (gn+2<Nc)? B[(size_t)gk*Nc + gn+2] : 0.f;
          v = make_float4(t0,t1,t2,0.f);
        }
        *(float4*)&Bs[kkk][nn4*4] = v;
      }
    }
    __syncthreads();
    #pragma unroll
    for (int kk = 0; kk < 16; ++kk) {
      float4 a4 = *(const float4*)&As[kk][ty*4];
      float4 b0 = *(const float4*)&Bs[kk][tx*8];
      float4 b1 = *(const float4*)&Bs[kk][tx*8+4];
      float av[4] = {a4.x,a4.y,a4.z,a4.w};
      float bv[8] = {b0.x,b0.y,b0.z,b0.w,b1.x,b1.y,b1.z,b1.w};
      #pragma unroll
      for (int i=0;i<4;++i)
        #pragma unroll
        for (int j=0;j<8;++j) acc[i][j] += av[i]*bv[j];
    }
    __syncthreads();
  }
  for (int i=0;i<4;++i){
    int gm = row0 + ty*4 + i; if (gm >= Mr) continue;
    for (int j=0;j<8;++j){
      int gn = col0 + tx*8 + j; if (gn >= Nc) continue;
      C[(size_t)gm*Nc + gn] = acc[i][j];
    }
  }
}

// Wt[f*(9*O) + s*O + o] = W[(f*9+s)*O + o]
template<int O>
__global__ void wreshape_k(const float* __restrict__ W, float* __restrict__ Wt, int F){
  int idx = blockIdx.x*256 + threadIdx.x;
  int total = F*9*O;
  if (idx >= total) return;
  int o = idx % O; int s = (idx / O) % 9; int f = idx / (9*O);
  Wt[idx] = W[(size_t)(f*9+s)*O + o];
}

// per-edge: out[dst[e],o] += (sum_s sh[e,s]*Y[src[e], s*O+o]) * lerp(T, el[e], o)
template<int O>
__global__ void econtract_k(const float* __restrict__ Y, const int* __restrict__ src,
                            const int* __restrict__ dst, const float* __restrict__ SH,
                            const float* __restrict__ EL, const float* __restrict__ T,
                            float* __restrict__ out, int nE){
  int idx = blockIdx.x*256 + threadIdx.x;
  if (idx >= nE*O) return;
  int e = idx / O, o = idx - e*O;
  const float* sr = SH + (size_t)e*9;
  const float* yr = Y + (size_t)src[e]*(9*O) + o;
  float acc = 0.0f;
  #pragma unroll
  for (int s = 0; s < 9; ++s) acc += sr[s] * yr[s*O];
  float rv = lerp_tab(T, EL[e], O, o);
  atomicAdd(&out[(size_t)dst[e]*O + o], acc * rv);
}

// ---------------- GCN pieces ----------------
__global__ void normact_k(const float* __restrict__ x, float* __restrict__ y){
  int idx = blockIdx.x*256 + threadIdx.x;
  if (idx >= N_*16) return;
  int n = idx >> 4, r = idx & 15;
  const float* xr = x + (size_t)n*144;
  float* yr = y + (size_t)n*144;
  float s = xr[r];
  yr[r] = s * sigm(fabsf(s));
  float v0 = xr[16+r*3], v1 = xr[16+r*3+1], v2 = xr[16+r*3+2];
  float gv = sigm(sqrtf(v0*v0+v1*v1+v2*v2));
  yr[16+r*3]=v0*gv; yr[16+r*3+1]=v1*gv; yr[16+r*3+2]=v2*gv;
  float t0=xr[64+r*5],t1=xr[64+r*5+1],t2=xr[64+r*5+2],t3=xr[64+r*5+3],t4=xr[64+r*5+4];
  float gt = sigm(sqrtf(t0*t0+t1*t1+t2*t2+t3*t3+t4*t4));
  yr[64+r*5]=t0*gt; yr[64+r*5+1]=t1*gt; yr[64+r*5+2]=t2*gt; yr[64+r*5+3]=t3*gt; yr[64+r*5+4]=t4*gt;
}

// ---------------- FNO ----------------
// fc0 with fused sigabs activation on mf
__global__ void fc0_k(const float* __restrict__ mf, const float* __restrict__ Wt,
                      const float* __restrict__ bb, float* __restrict__ h){
  int idx = blockIdx.x*256 + threadIdx.x;
  if (idx >= M_*16) return;
  int m = idx >> 4, o = idx & 15;
  int r = m % 8000;
  float fx = (float)(r/400)*0.05f, fy = (float)((r/20)%20)*0.05f, fz = (float)(r%20)*0.05f;
  const float* mfr = mf + (size_t)m*32;
  float acc = bb[o];
  #pragma unroll
  for (int j=0;j<32;++j){
    float v = mfr[j];
    v = v * sigm(fabsf(v));
    acc += v*Wt[j*16+o];
  }
  acc += fx*Wt[32*16+o] + fy*Wt[33*16+o] + fz*Wt[34*16+o];
  h[idx] = acc;
}

// LDS-transposed spectral weight reorder; block = (ky*20+kx, layer)
__global__ __launch_bounds__(256) void wreorder2_k(const float* __restrict__ wr, const float* __restrict__ wi,
                          float2* __restrict__ W2){
  __shared__ float2 tile[2560];
  int l = blockIdx.y;
  const float* wrl = wr + (size_t)l*1024000;
  const float* wil = wi + (size_t)l*1024000;
  int p = blockIdx.x;
  int ky = p/20, kx = p%20;
  int corner = ((kx>=10)?1:0) + ((ky>=10)?2:0);
  int base2 = corner*256;
  int soff = (kx%10)*100 + (ky%10)*10;
  for (int t = threadIdx.x; t < 2560; t += 256){
    int chunk = t/10, kz = t - chunk*10;
    size_t src = (size_t)(base2 + chunk)*1000 + soff + kz;
    tile[kz*256 + chunk] = make_float2(wrl[src], wil[src]);
  }
  __syncthreads();
  float2* dst = W2 + (size_t)l*1024000 + (size_t)p*2560;
  for (int t = threadIdx.x; t < 2560; t += 256) dst[t] = tile[t];
}

// stage A: z-DFT (keep kz 0..9) + y-DFT, per (b, X, chan-group-of-4)
__global__ __launch_bounds__(256) void zyfwd_k(const float* __restrict__ h, float2* __restrict__ cA){
  __shared__ float  pl[20][20][4];
  __shared__ float2 tz[20][10][4];
  __shared__ float2 tw[20];
  int tid = threadIdx.x;
  if (tid < 20){ float a = -6.283185307179586f*tid/20.0f; tw[tid] = make_float2(cosf(a), sinf(a)); }
  int bid = blockIdx.x;
  int b = bid / 80, rem = bid % 80;
  int X = rem >> 2, cg = rem & 3;
  const float* hp = h + (size_t)(b*20+X)*400*16 + cg*4;
  for (int t = tid; t < 400; t += 256) {
    int y = t/20, z = t%20;
    const float4 v = *(const float4*)(hp + (size_t)t*16);
    pl[y][z][0]=v.x; pl[y][z][1]=v.y; pl[y][z][2]=v.z; pl[y][z][3]=v.w;
  }
  __syncthreads();
  for (int t = tid; t < 800; t += 256) {
    int c = t & 3, kz = (t>>2)%10, y = t/40;
    float sr=0.0f, si=0.0f; int j=0;
    for (int z=0; z<20; ++z){
      float v = pl[y][z][c];
      float2 w = tw[j];
      sr += v*w.x; si += v*w.y;
      j += kz; if (j>=20) j-=20;
    }
    tz[y][kz][c] = make_float2(sr,si);
  }
  __syncthreads();
  for (int t = tid; t < 800; t += 256) {
    int c = t & 3, kz = (t>>2)%10, ky = t/40;
    float sr=0.0f, si=0.0f; int j=0;
    for (int y=0; y<20; ++y){
      float2 v = tz[y][kz][c];
      float2 w = tw[j];
      sr += v.x*w.x - v.y*w.y;
      si += v.x*w.y + v.y*w.x;
      j += ky; if (j>=20) j-=20;
    }
    cA[((size_t)((b*20+ky)*10+kz)*20 + X)*16 + cg*4+c] = make_float2(sr,si);
  }
}

// stage B: x-DFT -> channel mix -> x-inverse, per (b, ky, kz), reordered weights
__global__ __launch_bounds__(256) void xmix_k(const float2* __restrict__ cA, float2* __restrict__ cB,
                    const float2* __restrict__ W2){
  __shared__ float2 xin[16][20];
  __shared__ float2 Xf[20][16];
  __shared__ float2 Mx[20][16];
  __shared__ float2 twf[20], twi[20];
  int tid = threadIdx.x;
  if (tid < 20){
    float a = -6.283185307179586f*tid/20.0f;
    twf[tid] = make_float2(cosf(a), sinf(a));
    twi[tid] = make_float2(cosf(a), -sinf(a));
  }
  int bid = blockIdx.x;
  int b = bid/200, rem = bid%200;
  int ky = rem/10, kz = rem%10;
  const float2* src = cA + (size_t)((b*20+ky)*10+kz)*320;
  for (int t = tid; t < 320; t += 256){
    int x = t/16, i = t%16;
    xin[i][x] = src[t];
  }
  __syncthreads();
  for (int t = tid; t < 320; t += 256){
    int kx = t/16, i = t%16;
    float sr=0.0f, si=0.0f; int j=0;
    for (int x=0;x<20;++x){
      float2 v = xin[i][x]; float2 w = twf[j];
      sr += v.x*w.x - v.y*w.y; si += v.x*w.y + v.y*w.x;
      j += kx; if (j>=20) j-=20;
    }
    Xf[kx][i] = make_float2(sr,si);
  }
  __syncthreads();
  for (int t = tid; t < 320; t += 256){
    int kx = t/16, o = t%16;
    const float2* wp = W2 + ((size_t)(ky*20+kx)*10 + kz)*256 + o;
    float sr=0.0f, si=0.0f;
    #pragma unroll
    for (int i=0;i<16;++i){
      float2 a = Xf[kx][i];
      float2 w = wp[i*16];
      sr += a.x*w.x - a.y*w.y;
      si += a.x*w.y + a.y*w.x;
    }
    Mx[kx][o] = make_float2(sr,si);
  }
  __syncthreads();
  for (int t = tid; t < 320; t += 256){
    int x = t/16, o = t%16;
    float sr=0.0f, si=0.0f; int j=0;
    for (int kx=0;kx<20;++kx){
      float2 v = Mx[kx][o]; float2 w = twi[j];
      sr += v.x*w.x - v.y*w.y; si += v.x*w.y + v.y*w.x;
      j += x; if (j>=20) j-=20;
    }
    cB[((size_t)((b*20+x)*20+ky)*10+kz)*16 + o] = make_float2(sr,si);
  }
}

// stage C: y-inverse + z-inverse(real, irfft semantics), per (b, X, chan-group)
__global__ __launch_bounds__(256) void yzinv_k(const float2* __restrict__ cB, float* __restrict__ spec){
  __shared__ float2 ci[20][10][4];
  __shared__ float2 ty[20][10][4];
  __shared__ float2 twi[20];
  int tid = threadIdx.x;
  if (tid < 20){ float a = 6.283185307179586f*tid/20.0f; twi[tid] = make_float2(cosf(a), sinf(a)); }
  int bid = blockIdx.x;
  int b = bid/80, rem = bid%80;
  int X = rem>>2, cg = rem&3;
  const float2* src = cB + (size_t)(b*20+X)*200*16;
  for (int t = tid; t < 800; t += 256){
    int c = t&3, kz = (t>>2)%10, ky = t/40;
    ci[ky][kz][c] = src[(size_t)(ky*10+kz)*16 + cg*4+c];
  }
  __syncthreads();
  for (int t = tid; t < 800; t += 256){
    int c = t&3, kz = (t>>2)%10, y = t/40;
    float sr=0.0f, si=0.0f; int j=0;
    for (int ky=0;ky<20;++ky){
      float2 v = ci[ky][kz][c]; float2 w = twi[j];
      sr += v.x*w.x - v.y*w.y; si += v.x*w.y + v.y*w.x;
      j += y; if (j>=20) j-=20;
    }
    ty[y][kz][c] = make_float2(sr,si);
  }
  __syncthreads();
  float* dst = spec + (size_t)(b*20+X)*400*16 + cg*4;
  for (int t = tid; t < 1600; t += 256){
    int c = t&3, z = (t>>2)%20, y = t/80;
    float acc = ty[y][0][c].x;   // kz=0: w=1, Im ignored
    float a2 = 0.0f; int jj = 0;
    for (int kz=1; kz<10; ++kz){
      jj += z; if (jj>=20) jj-=20;
      float2 v = ty[y][kz][c]; float2 w = twi[jj];
      a2 += v.x*w.x - v.y*w.y;
    }
    acc += 2.0f*a2;
    dst[(size_t)(y*20+z)*16 + c] = acc * (1.0f/8000.0f);
  }
}

// fused FNO tail, 2-way k-split (bank-conflict-free)
__global__ __launch_bounds__(256) void ffn3_k(const float* __restrict__ spec, const float* __restrict__ h,
                     const float* __restrict__ pw, const float* __restrict__ ff1,
                     const float* __restrict__ ff2, float* __restrict__ hout){
  __shared__ float spw[256];
  __shared__ float sf1[1024];
  __shared__ float sf2[1024];
  __shared__ float h2s[128][17];
  __shared__ float red[2][128][17];
  int tid = threadIdx.x;
  spw[tid] = pw[tid];
  for (int t = tid; t < 1024; t += 256){ sf1[t]=ff1[t]; sf2[t]=ff2[t]; }
  int rl = tid >> 1, q = tid & 1;
  int m = blockIdx.x*128 + rl;
  const float* hr = h + (size_t)m*16;
  float hl[16];
  #pragma unroll
  for (int i=0;i<16;++i) hl[i] = hr[i];
  __syncthreads();
  const float* sp = spec + (size_t)m*16;
  #pragma unroll
  for (int c=0;c<8;++c){
    int o = q*8+c;
    float acc = sp[o];
    #pragma unroll
    for (int i=0;i<16;++i) acc += hl[i]*spw[i*16+o];
    h2s[rl][o] = geluf(acc);
  }
  __syncthreads();
  float h2l[16];
  #pragma unroll
  for (int i=0;i<16;++i) h2l[i] = h2s[rl][i];
  float part[16] = {};
  for (int kk=0;kk<32;++kk){
    int k = q*32+kk;
    float a0=0.0f, a1=0.0f;
    #pragma unroll
    for (int i=0;i<8;++i){ a0 += h2l[i]*sf1[i*64+k]; a1 += h2l[8+i]*sf1[(8+i)*64+k]; }
    float tk = geluf(a0+a1);
    #pragma unroll
    for (int o=0;o<16;++o) part[o] += tk*sf2[k*16+o];
  }
  #pragma unroll
  for (int o=0;o<16;++o) red[q][rl][o] = part[o];
  __syncthreads();
  #pragma unroll
  for (int c=0;c<8;++c){
    int o = q*8+c;
    hout[(size_t)m*16+o] = h2s[rl][o] + red[0][rl][o] + red[1][rl][o];
  }
}

// fused final projection, 2-way k-split
__global__ __launch_bounds__(256) void fctail3_k(const float* __restrict__ h, const float* __restrict__ fc1,
                        const float* __restrict__ fc2, float* __restrict__ outm){
  __shared__ float s1[2048];
  __shared__ float s2[2048];
  __shared__ float red[2][128][17];
  int tid = threadIdx.x;
  for (int t = tid; t < 2048; t += 256){ s1[t]=fc1[t]; s2[t]=fc2[t]; }
  int rl = tid >> 1, q = tid & 1;
  int m = blockIdx.x*128 + rl;
  const float* hr = h + (size_t)m*16;
  float hl[16];
  #pragma unroll
  for (int i=0;i<16;++i) hl[i] = hr[i];
  __syncthreads();
  float part[16] = {};
  for (int kk=0;kk<64;++kk){
    int k = q*64+kk;
    float a0=0.0f, a1=0.0f;
    #pragma unroll
    for (int i=0;i<8;++i){ a0 += hl[i]*s1[i*128+k]; a1 += hl[8+i]*s1[(8+i)*128+k]; }
    float tk = geluf(a0+a1);
    #pragma unroll
    for (int o=0;o<16;++o) part[o] += tk*s2[k*16+o];
  }
  #pragma unroll
  for (int o=0;o<16;++o) red[q][rl][o] = part[o];
  __syncthreads();
  #pragma unroll
  for (int c=0;c<8;++c){
    int o = q*8+c;
    outm[(size_t)m*16+o] = red[0][rl][o] + red[1][rl][o];
  }
}

// ---------------- m2a + final ----------------
__global__ void m2a_k(const float* __restrict__ mf2, const int* __restrict__ mdst,
                      const int* __restrict__ asrc, const float* __restrict__ sh2,
                      const float* __restrict__ Wt, const float* __restrict__ EL,
                      const float* __restrict__ T, float* __restrict__ af){
  int e = blockIdx.x*256 + threadIdx.x;
  if (e >= E2_) return;
  const float* xr = mf2 + (size_t)mdst[e]*16;
  const float* sr = sh2 + (size_t)e*9;
  float sh[9];
  #pragma unroll
  for (int s=0;s<9;++s) sh[s] = sr[s];
  float acc = 0.0f;
  #pragma unroll
  for (int f=0;f<16;++f) {
    float xv = xr[f];
    float dot = 0.0f;
    #pragma unroll
    for (int s=0;s<9;++s) dot += sh[s]*Wt[f*9+s];
    acc += xv*dot;
  }
  float rv = lerp_tab(T, EL[e], 1, 0);
  atomicAdd(&af[asrc[e]], acc*rv);
}

__global__ void bsum_k(const float* __restrict__ af, const int* __restrict__ batch,
                       float* __restrict__ out){
  int n = blockIdx.x*256 + threadIdx.x;
  if (n >= N_) return;
  atomicAdd(&out[batch[n]], af[n]);
}

} // namespace

extern "C" void kernel_launch(void* const* d_in, const int* in_sizes, int n_in,
                              void* d_out, int out_size, void* d_ws, size_t ws_size,
                              hipStream_t stream) {
  (void)in_sizes; (void)n_in; (void)out_size; (void)ws_size;
  const float* pos   = (const float*)d_in[0];
  const float* cell  = (const float*)d_in[1];
  const int*   an    = (const int*)d_in[2];
  const int*   batch = (const int*)d_in[3];
  const int*   esrc  = (const int*)d_in[4];
  const int*   edst  = (const int*)d_in[5];
  const int*   asrc  = (const int*)d_in[6];
  const int*   mdst  = (const int*)d_in[7];
  const float* emb   = (const float*)d_in[8];
  const float* g0_W  = (const float*)d_in[9];
  const float* g0_Wsc= (const float*)d_in[10];
  const float* g0_m1 = (const float*)d_in[11];
  const float* g0_m2 = (const float*)d_in[12];
  const float* g0_m3 = (const float*)d_in[13];
  const float* g12_W = (const float*)d_in[14];
  const float* g12_Wsc=(const float*)d_in[15];
  const float* g12_m1= (const float*)d_in[16];
  const float* g12_m2= (const float*)d_in[17];
  const float* g12_m3= (const float*)d_in[18];
  const float* a2m_W = (const float*)d_in[19];
  const float* a2m_m1= (const float*)d_in[20];
  const float* a2m_m2= (const float*)d_in[21];
  const float* a2m_m3= (const float*)d_in[22];
  const float* m2a_W = (const float*)d_in[23];
  const float* m2a_m1= (const float*)d_in[24];
  const float* m2a_m2= (const float*)d_in[25];
  const float* m2a_m3= (const float*)d_in[26];
  const float* fc0_W = (const float*)d_in[27];
  const float* fc0_b = (const float*)d_in[28];
  const float* sw_r  = (const float*)d_in[29];
  const float* sw_i  = (const float*)d_in[30];
  const float* pw    = (const float*)d_in[31];
  const float* ff1   = (const float*)d_in[32];
  const float* ff2   = (const float*)d_in[33];
  const float* fc1   = (const float*)d_in[34];
  const float* fc2   = (const float*)d_in[35];
  float* out = (float*)d_out;

  float* Wp = (float*)d_ws;
  size_t off = 0;
  auto alloc = [&](size_t n){ float* p = Wp + off; off += n; return p; };
  float* meshpos = alloc((size_t)M_*3);
  float* she   = alloc((size_t)E_*9);
  float* ELe   = alloc((size_t)E_);
  float* sh2   = alloc((size_t)E2_*9);
  float* EL2   = alloc((size_t)E2_);
  float* x16   = alloc((size_t)N_*16);
  float* xatom = alloc((size_t)N_*144);
  float* xact  = alloc((size_t)N_*144);
  float* Wt    = alloc((size_t)144*1296);        // reshaped expanded weights
  float* Yg    = alloc((size_t)N_*1296);         // per-atom Y
  float* mf    = alloc((size_t)M_*32);
  float* hbuf  = alloc((size_t)M_*16);
  float* htmp  = alloc((size_t)M_*16);
  float2* cA   = (float2*)alloc(1024000);
  float2* cB   = (float2*)alloc(1024000);
  float2* W2   = (float2*)alloc((size_t)3*2048000); // reordered spectral weights (3 layers)
  float* af    = alloc((size_t)N_);
  float* Es    = alloc((size_t)NT_*64);
  float* H1g   = alloc((size_t)5*NT_*128);
  float* H2g   = alloc((size_t)5*NT_*128);
  float* T0    = alloc((size_t)NT_*144);
  float* T1    = alloc((size_t)NT_*144);
  float* T2    = alloc((size_t)NT_*144);
  float* T3    = alloc((size_t)NT_*32);
  float* T4    = alloc((size_t)NT_*1);

  auto g1 = [](int n){ return dim3((unsigned)((n+255)/256)); };
  auto gg2 = [](int Mr, int Nc){ return dim3((unsigned)((Nc+127)/128), (unsigned)((Mr+63)/64)); };

  // zero accumulators
  zero_k<<<g1(8), 256, 0, stream>>>(out, 8);
  zero_k<<<g1(N_), 256, 0, stream>>>(af, N_);
  zero_k<<<g1(M_*32), 256, 0, stream>>>(mf, M_*32);

  // geometry
  meshpos_k<<<g1(M_), 256, 0, stream>>>(cell, meshpos);
  edge_geom2_k<<<g1(E_), 256, 0, stream>>>(pos, esrc, pos, edst, she, ELe, E_);
  edge_geom2_k<<<g1(E2_), 256, 0, stream>>>(meshpos, mdst, pos, asrc, sh2, EL2, E2_);
  gather_emb_k<<<g1(N_*16), 256, 0, stream>>>(emb, an, x16);

  // spectral weight reorder (LDS transpose, all 3 layers in one launch)
  wreorder2_k<<<dim3(400,3), 256, 0, stream>>>(sw_r, sw_i, W2);

  // ---- radial tables via 3 batched GEMMs ----
  {
    es_k<<<g1(NT_*64), 256, 0, stream>>>(Es);
    BG l1, l2, l3;
    const float* m1s[5] = {g0_m1, g12_m1, g12_m1+(size_t)64*128, a2m_m1, m2a_m1};
    const float* m2s[5] = {g0_m2, g12_m2, g12_m2+(size_t)128*128, a2m_m2, m2a_m2};
    const float* m3s[5] = {g0_m3, g12_m3, g12_m3+(size_t)128*144, a2m_m3, m2a_m3};
    float* Ts[5] = {T0, T1, T2, T3, T4};
    int NOs[5] = {144, 144, 144, 32, 1};
    for (int c = 0; c < 5; ++c) {
      l1.A[c] = Es;                      l1.B[c] = m1s[c]; l1.C[c] = H1g + (size_t)c*NT_*128; l1.Nc[c] = 128;
      l2.A[c] = H1g + (size_t)c*NT_*128; l2.B[c] = m2s[c]; l2.C[c] = H2g + (size_t)c*NT_*128; l2.Nc[c] = 128;
      l3.A[c] = H2g + (size_t)c*NT_*128; l3.B[c] = m3s[c]; l3.C[c] = Ts[c];                   l3.Nc[c] = NOs[c];
    }
    l1.K = 64; l2.K = 128; l3.K = 128;
    bgemm_k<1><<<dim3(2, NT_/64, 5), 256, 0, stream>>>(l1);
    bgemm_k<1><<<dim3(2, NT_/64, 5), 256, 0, stream>>>(l2);
    bgemm_k<0><<<dim3(3, NT_/64, 5), 256, 0, stream>>>(l3);
  }

  // ---- g0 ----
  wreshape_k<144><<<g1(16*9*144), 256, 0, stream>>>(g0_W, Wt, 16);
  gemm128_k<<<gg2(N_,1296), 256, 0, stream>>>(x16, Wt, Yg, N_, 16, 1296);
  gemm128_k<<<gg2(N_,144), 256, 0, stream>>>(x16, g0_Wsc, xatom, N_, 16, 144);
  econtract_k<144><<<g1(E_*144), 256, 0, stream>>>(Yg, esrc, edst, she, ELe, T0, xatom, E_);

  // ---- g12 x2 ----
  for (int i = 0; i < 2; ++i) {
    normact_k<<<g1(N_*16), 256, 0, stream>>>(xatom, xact);
    wreshape_k<144><<<g1(144*9*144), 256, 0, stream>>>(g12_W + (size_t)i*1296*144, Wt, 144);
    gemm128_k<<<gg2(N_,1296), 256, 0, stream>>>(xact, Wt, Yg, N_, 144, 1296);
    gemm128_k<<<gg2(N_,144), 256, 0, stream>>>(xact, g12_Wsc + (size_t)i*144*144, xatom, N_, 144, 144);
    econtract_k<144><<<g1(E_*144), 256, 0, stream>>>(Yg, esrc, edst, she, ELe, (i==0)?T1:T2, xatom, E_);
  }

  // ---- a2m ----
  wreshape_k<32><<<g1(144*9*32), 256, 0, stream>>>(a2m_W, Wt, 144);
  gemm128_k<<<gg2(N_,288), 256, 0, stream>>>(xatom, Wt, Yg, N_, 144, 288);
  econtract_k<32><<<g1(E2_*32), 256, 0, stream>>>(Yg, asrc, mdst, sh2, EL2, T3, mf, E2_);

  // ---- FNO ----
  fc0_k<<<g1(M_*16), 256, 0, stream>>>(mf, fc0_W, fc0_b, hbuf);
  for (int l = 0; l < 3; ++l) {
    zyfwd_k<<<dim3(640), 256, 0, stream>>>(hbuf, cA);
    xmix_k<<<dim3(1600), 256, 0, stream>>>(cA, cB, W2 + (size_t)l*1024000);
    yzinv_k<<<dim3(640), 256, 0, stream>>>(cB, htmp);
    ffn3_k<<<dim3(500), 256, 0, stream>>>(htmp, hbuf, pw + (size_t)l*256,
                                          ff1 + (size_t)l*1024, ff2 + (size_t)l*1024, hbuf);
  }
  fctail3_k<<<dim3(500), 256, 0, stream>>>(hbuf, fc1, fc2, htmp);

  // ---- m2a + batch reduce ----
  m2a_k<<<g1(E2_), 256, 0, stream>>>(htmp, mdst, asrc, sh2, m2a_W, EL2, T4, af);
  bsum_k<<<g1(N_), 256, 0, stream>>>(af, batch, out);
}

// Round 11
// 509.310 us; speedup vs baseline: 1.1984x; 1.1984x over previous
//
#include <hip/hip_runtime.h>
#include <math.h>

#define DEVI __device__ __forceinline__

namespace {

constexpr int N_  = 2048;
constexpr int E_  = 32768;
constexpr int E2_ = 65536;
constexpr int M_  = 64000;   // 8 * 20^3
constexpr int NT_ = 2048;    // radial table resolution
constexpr float TMAX_ = 5.5f;
constexpr float TH_ = TMAX_ / NT_;

using bf16x8 = __attribute__((ext_vector_type(8))) short;
using f32x4  = __attribute__((ext_vector_type(4))) float;

DEVI float sigm(float x)  { return 1.0f/(1.0f+expf(-x)); }
DEVI float geluf(float x) {
  float t = tanhf(0.7978845608028654f*(x + 0.044715f*x*x*x));
  return 0.5f*x*(1.0f+t);
}

DEVI unsigned short bf16rn(float x){
  unsigned u = __float_as_uint(x);
  unsigned r = u + 0x7FFFu + ((u>>16)&1u);
  return (unsigned short)(r>>16);
}
DEVI void bf16split(float x, unsigned short& h, unsigned short& l){
  h = bf16rn(x);
  float hf = __uint_as_float(((unsigned)h)<<16);
  l = bf16rn(x - hf);
}

// ---------------- utility ----------------
__global__ void zero_k(float* __restrict__ p, int n){
  int i = blockIdx.x*256 + threadIdx.x;
  if (i < n) p[i] = 0.0f;
}

__global__ void meshpos_k(const float* __restrict__ cell, float* __restrict__ mp){
  int m = blockIdx.x*256 + threadIdx.x;
  if (m >= M_) return;
  int b = m/8000, r = m%8000;
  float fx = (float)(r/400)    * 0.05f;
  float fy = (float)((r/20)%20)* 0.05f;
  float fz = (float)(r%20)     * 0.05f;
  const float* c = cell + b*9;
  mp[(size_t)m*3+0] = fx*c[0] + fy*c[3] + fz*c[6];
  mp[(size_t)m*3+1] = fx*c[1] + fy*c[4] + fz*c[7];
  mp[(size_t)m*3+2] = fx*c[2] + fy*c[5] + fz*c[8];
}

// edge geometry: ev = P[pi[e]] - Q[qi[e]]; writes sh (9) and el (1)
__global__ void edge_geom2_k(const float* __restrict__ Ppos, const int* __restrict__ pi,
                             const float* __restrict__ Qpos, const int* __restrict__ qi,
                             float* __restrict__ sh, float* __restrict__ el_out, int nE){
  int e = blockIdx.x*256 + threadIdx.x;
  if (e >= nE) return;
  int a = pi[e], b = qi[e];
  float ex = Ppos[(size_t)a*3+0] - Qpos[(size_t)b*3+0];
  float ey = Ppos[(size_t)a*3+1] - Qpos[(size_t)b*3+1];
  float ez = Ppos[(size_t)a*3+2] - Qpos[(size_t)b*3+2];
  float el = sqrtf(ex*ex+ey*ey+ez*ez) + 1e-8f;
  el_out[e] = el;
  float x = ex/el, y = ey/el, z = ez/el;
  float* s = sh + (size_t)e*9;
  s[0] = 0.28209479177387814f;
  s[1] = 0.4886025119029199f*y;
  s[2] = 0.4886025119029199f*z;
  s[3] = 0.4886025119029199f*x;
  s[4] = 1.0925484305920792f*x*y;
  s[5] = 1.0925484305920792f*y*z;
  s[6] = 0.31539156525252005f*(3.0f*z*z-1.0f);
  s[7] = 1.0925484305920792f*x*z;
  s[8] = 0.5462742152960396f*(x*x-y*y);
}

__global__ void gather_emb_k(const float* __restrict__ emb, const int* __restrict__ an,
                             float* __restrict__ x16){
  int idx = blockIdx.x*256 + threadIdx.x;
  if (idx >= N_*16) return;
  int n = idx >> 4, f = idx & 15;
  x16[idx] = emb[(size_t)an[n]*16 + f];
}

// ---------------- radial tables ----------------
__global__ void es_k(float* __restrict__ Es){
  int idx = blockIdx.x*256 + threadIdx.x;
  if (idx >= NT_*64) return;
  int r = idx >> 6, k = idx & 63;
  const float step = 5.0f/63.0f;
  float d = (r*TH_ - k*step)/step;
  Es[idx] = expf(-d*d)*(8.0f/1.12f);
}

DEVI float lerp_tab(const float* __restrict__ T, float el, int O, int o){
  float u = el * (1.0f/TH_);
  u = fminf(u, (float)(NT_-1));
  int i = (int)u; if (i > NT_-2) i = NT_-2;
  float f = u - (float)i;
  float t0 = T[(size_t)i*O + o];
  float t1 = T[(size_t)(i+1)*O + o];
  return t0 + f*(t1 - t0);
}

// ---------------- table GEMM (fp32, batched) ----------------
struct BG {
  const float* A[5]; const float* B[5]; float* C[5];
  int K; int Nc[5];
};
template<int ACT>
__global__ __launch_bounds__(256) void bgemm_k(BG args){
  int chain = blockIdx.z;
  const float* A = args.A[chain];
  const float* Bm = args.B[chain];
  float* C = args.C[chain];
  int K = args.K, Nc = args.Nc[chain];
  int row0 = blockIdx.y*64, col0 = blockIdx.x*64;
  if (col0 >= Nc) return;
  __shared__ float As[16][72];
  __shared__ float Bs[16][72];
  int tid = threadIdx.x;
  int tx = tid & 15, ty = tid >> 4;
  float acc[4][4] = {};
  for (int k0 = 0; k0 < K; k0 += 16) {
    { int kk = tid & 15; int mloc = tid >> 4;
      int gk = k0 + kk;
      #pragma unroll
      for (int p = 0; p < 4; ++p) {
        int m = mloc + p*16; int gm = row0 + m;
        As[kk][m] = A[(size_t)gm*K + gk];
      } }
    { int nn = tid & 63; int kl = tid >> 6;
      #pragma unroll
      for (int p = 0; p < 4; ++p) {
        int kk = kl + p*4; int gk = k0 + kk; int gn = col0 + nn;
        Bs[kk][nn] = (gn < Nc) ? Bm[(size_t)gk*Nc + gn] : 0.0f;
      } }
    __syncthreads();
    #pragma unroll
    for (int kk = 0; kk < 16; ++kk) {
      float4 a4 = *(const float4*)&As[kk][ty*4];
      float4 b4 = *(const float4*)&Bs[kk][tx*4];
      float a[4] = {a4.x,a4.y,a4.z,a4.w};
      float b[4] = {b4.x,b4.y,b4.z,b4.w};
      #pragma unroll
      for (int i=0;i<4;++i)
        #pragma unroll
        for (int j=0;j<4;++j) acc[i][j] += a[i]*b[j];
    }
    __syncthreads();
  }
  for (int i=0;i<4;++i) {
    int gm = row0 + ty*4+i;
    for (int j=0;j<4;++j) {
      int gn = col0 + tx*4+j; if (gn >= Nc) continue;
      float v = acc[i][j];
      if (ACT==1) v = v*sigm(v);
      C[(size_t)gm*Nc + gn] = v;
    }
  }
}

// ---------------- MFMA bf16x3 GEMM path ----------------
// A (M x K fp32) -> padded bf16 hi/lo (M x KP)
__global__ void convA_k(const float* __restrict__ x, unsigned short* __restrict__ hi,
                        unsigned short* __restrict__ lo, int Mr, int K, int KP){
  int idx = blockIdx.x*256 + threadIdx.x;
  if (idx >= Mr*KP) return;
  int n = idx / KP, k = idx - n*KP;
  unsigned short h = 0, l = 0;
  if (k < K) bf16split(x[(size_t)n*K + k], h, l);
  hi[idx] = h; lo[idx] = l;
}

// B (K x N fp32 row-major) -> transposed padded bf16 hi/lo (N x KP)
__global__ void convT_k(const float* __restrict__ B, unsigned short* __restrict__ hi,
                        unsigned short* __restrict__ lo, int K, int Nc, int KP){
  int idx = blockIdx.x*256 + threadIdx.x;
  if (idx >= Nc*KP) return;
  int n = idx / KP, k = idx - n*KP;
  unsigned short h = 0, l = 0;
  if (k < K) bf16split(B[(size_t)k*Nc + n], h, l);
  hi[idx] = h; lo[idx] = l;
}

// expanded W reshape + transpose + split: dst[(s*O+o)*KP + f] = W[(f*9+s)*O + o]
template<int O>
__global__ void wreshapeT_k(const float* __restrict__ W, unsigned short* __restrict__ hi,
                            unsigned short* __restrict__ lo, int F, int KP){
  int idx = blockIdx.x*256 + threadIdx.x;
  int total = 9*O*KP;
  if (idx >= total) return;
  int n = idx / KP, f = idx - n*KP;
  unsigned short h = 0, l = 0;
  if (f < F){
    int s = n / O, o = n - s*O;
    bf16split(W[(size_t)(f*9+s)*O + o], h, l);
  }
  hi[idx] = h; lo[idx] = l;
}

// norm_act -> padded bf16 hi/lo A (2048 x 160)
__global__ void normact_bf_k(const float* __restrict__ x, unsigned short* __restrict__ hi,
                             unsigned short* __restrict__ lo){
  int idx = blockIdx.x*256 + threadIdx.x;
  if (idx >= N_*16) return;
  int n = idx >> 4, r = idx & 15;
  const float* xr = x + (size_t)n*144;
  unsigned short* hr = hi + (size_t)n*160;
  unsigned short* lr = lo + (size_t)n*160;
  unsigned short h, l;
  float s = xr[r];
  bf16split(s * sigm(fabsf(s)), h, l); hr[r]=h; lr[r]=l;
  float v0 = xr[16+r*3], v1 = xr[16+r*3+1], v2 = xr[16+r*3+2];
  float gv = sigm(sqrtf(v0*v0+v1*v1+v2*v2));
  bf16split(v0*gv,h,l); hr[16+r*3]=h;   lr[16+r*3]=l;
  bf16split(v1*gv,h,l); hr[16+r*3+1]=h; lr[16+r*3+1]=l;
  bf16split(v2*gv,h,l); hr[16+r*3+2]=h; lr[16+r*3+2]=l;
  float t0=xr[64+r*5],t1=xr[64+r*5+1],t2=xr[64+r*5+2],t3=xr[64+r*5+3],t4=xr[64+r*5+4];
  float gt = sigm(sqrtf(t0*t0+t1*t1+t2*t2+t3*t3+t4*t4));
  bf16split(t0*gt,h,l); hr[64+r*5]=h;   lr[64+r*5]=l;
  bf16split(t1*gt,h,l); hr[64+r*5+1]=h; lr[64+r*5+1]=l;
  bf16split(t2*gt,h,l); hr[64+r*5+2]=h; lr[64+r*5+2]=l;
  bf16split(t3*gt,h,l); hr[64+r*5+3]=h; lr[64+r*5+3]=l;
  bf16split(t4*gt,h,l); hr[64+r*5+4]=h; lr[64+r*5+4]=l;
  hr[144+r] = 0; lr[144+r] = 0;   // pad cols 144..159
}

// MFMA GEMM: C(M x N fp32) = A @ B with bf16x3 split operands.
// A: hi/lo M x KP; BT: hi/lo N x KP (B transposed). One wave per 16x16 tile.
__global__ __launch_bounds__(256) void mgemm_k(const unsigned short* __restrict__ Ah,
                     const unsigned short* __restrict__ Al,
                     const unsigned short* __restrict__ BTh,
                     const unsigned short* __restrict__ Bl,
                     float* __restrict__ C, int Mr, int KP, int Nc){
  int tilesN = Nc >> 4;
  int wid = ((blockIdx.x*256 + threadIdx.x) >> 6);
  int tm = wid / tilesN, tn = wid - tm*tilesN;
  if (tm*16 >= Mr) return;
  int lane = threadIdx.x & 63;
  int l15 = lane & 15;
  int kb  = (lane >> 4) * 8;
  const unsigned short* ah = Ah + (size_t)(tm*16 + l15)*KP + kb;
  const unsigned short* al = Al + (size_t)(tm*16 + l15)*KP + kb;
  const unsigned short* bh = BTh + (size_t)(tn*16 + l15)*KP + kb;
  const unsigned short* bl = Bl  + (size_t)(tn*16 + l15)*KP + kb;
  f32x4 acc = {0.f,0.f,0.f,0.f};
  for (int k0 = 0; k0 < KP; k0 += 32) {
    bf16x8 a_h = *(const bf16x8*)(ah + k0);
    bf16x8 a_l = *(const bf16x8*)(al + k0);
    bf16x8 b_h = *(const bf16x8*)(bh + k0);
    bf16x8 b_l = *(const bf16x8*)(bl + k0);
    acc = __builtin_amdgcn_mfma_f32_16x16x32_bf16(a_h, b_h, acc, 0, 0, 0);
    acc = __builtin_amdgcn_mfma_f32_16x16x32_bf16(a_h, b_l, acc, 0, 0, 0);
    acc = __builtin_amdgcn_mfma_f32_16x16x32_bf16(a_l, b_h, acc, 0, 0, 0);
  }
  int r0 = tm*16 + (lane>>4)*4;
  int co = tn*16 + l15;
  #pragma unroll
  for (int r = 0; r < 4; ++r){
    C[(size_t)(r0+r)*Nc + co] = acc[r];
  }
}

// per-edge: out[dst[e],o] += (sum_s sh[e,s]*Y[src[e], s*O+o]) * lerp(T, el[e], o)
template<int O>
__global__ void econtract_k(const float* __restrict__ Y, const int* __restrict__ src,
                            const int* __restrict__ dst, const float* __restrict__ SH,
                            const float* __restrict__ EL, const float* __restrict__ T,
                            float* __restrict__ out, int nE){
  int idx = blockIdx.x*256 + threadIdx.x;
  if (idx >= nE*O) return;
  int e = idx / O, o = idx - e*O;
  const float* sr = SH + (size_t)e*9;
  const float* yr = Y + (size_t)src[e]*(9*O) + o;
  float acc = 0.0f;
  #pragma unroll
  for (int s = 0; s < 9; ++s) acc += sr[s] * yr[s*O];
  float rv = lerp_tab(T, EL[e], O, o);
  atomicAdd(&out[(size_t)dst[e]*O + o], acc * rv);
}

// ---------------- FNO ----------------
// fc0 with fused sigabs activation on mf
__global__ void fc0_k(const float* __restrict__ mf, const float* __restrict__ Wt,
                      const float* __restrict__ bb, float* __restrict__ h){
  int idx = blockIdx.x*256 + threadIdx.x;
  if (idx >= M_*16) return;
  int m = idx >> 4, o = idx & 15;
  int r = m % 8000;
  float fx = (float)(r/400)*0.05f, fy = (float)((r/20)%20)*0.05f, fz = (float)(r%20)*0.05f;
  const float* mfr = mf + (size_t)m*32;
  float acc = bb[o];
  #pragma unroll
  for (int j=0;j<32;++j){
    float v = mfr[j];
    v = v * sigm(fabsf(v));
    acc += v*Wt[j*16+o];
  }
  acc += fx*Wt[32*16+o] + fy*Wt[33*16+o] + fz*Wt[34*16+o];
  h[idx] = acc;
}

// LDS-transposed spectral weight reorder; block = (ky*20+kx, layer)
__global__ __launch_bounds__(256) void wreorder2_k(const float* __restrict__ wr, const float* __restrict__ wi,
                          float2* __restrict__ W2){
  __shared__ float2 tile[2560];
  int l = blockIdx.y;
  const float* wrl = wr + (size_t)l*1024000;
  const float* wil = wi + (size_t)l*1024000;
  int p = blockIdx.x;
  int ky = p/20, kx = p%20;
  int corner = ((kx>=10)?1:0) + ((ky>=10)?2:0);
  int base2 = corner*256;
  int soff = (kx%10)*100 + (ky%10)*10;
  for (int t = threadIdx.x; t < 2560; t += 256){
    int chunk = t/10, kz = t - chunk*10;
    size_t src = (size_t)(base2 + chunk)*1000 + soff + kz;
    tile[kz*256 + chunk] = make_float2(wrl[src], wil[src]);
  }
  __syncthreads();
  float2* dst = W2 + (size_t)l*1024000 + (size_t)p*2560;
  for (int t = threadIdx.x; t < 2560; t += 256) dst[t] = tile[t];
}

// stage A: z-DFT (keep kz 0..9) + y-DFT, per (b, X, chan-group-of-4)
__global__ __launch_bounds__(256) void zyfwd_k(const float* __restrict__ h, float2* __restrict__ cA){
  __shared__ float  pl[20][20][4];
  __shared__ float2 tz[20][10][4];
  __shared__ float2 tw[20];
  int tid = threadIdx.x;
  if (tid < 20){ float a = -6.283185307179586f*tid/20.0f; tw[tid] = make_float2(cosf(a), sinf(a)); }
  int bid = blockIdx.x;
  int b = bid / 80, rem = bid % 80;
  int X = rem >> 2, cg = rem & 3;
  const float* hp = h + (size_t)(b*20+X)*400*16 + cg*4;
  for (int t = tid; t < 400; t += 256) {
    int y = t/20, z = t%20;
    const float4 v = *(const float4*)(hp + (size_t)t*16);
    pl[y][z][0]=v.x; pl[y][z][1]=v.y; pl[y][z][2]=v.z; pl[y][z][3]=v.w;
  }
  __syncthreads();
  for (int t = tid; t < 800; t += 256) {
    int c = t & 3, kz = (t>>2)%10, y = t/40;
    float sr=0.0f, si=0.0f; int j=0;
    for (int z=0; z<20; ++z){
      float v = pl[y][z][c];
      float2 w = tw[j];
      sr += v*w.x; si += v*w.y;
      j += kz; if (j>=20) j-=20;
    }
    tz[y][kz][c] = make_float2(sr,si);
  }
  __syncthreads();
  for (int t = tid; t < 800; t += 256) {
    int c = t & 3, kz = (t>>2)%10, ky = t/40;
    float sr=0.0f, si=0.0f; int j=0;
    for (int y=0; y<20; ++y){
      float2 v = tz[y][kz][c];
      float2 w = tw[j];
      sr += v.x*w.x - v.y*w.y;
      si += v.x*w.y + v.y*w.x;
      j += ky; if (j>=20) j-=20;
    }
    cA[((size_t)((b*20+ky)*10+kz)*20 + X)*16 + cg*4+c] = make_float2(sr,si);
  }
}

// stage B: x-DFT -> channel mix -> x-inverse, per (b, ky, kz), reordered weights
__global__ __launch_bounds__(256) void xmix_k(const float2* __restrict__ cA, float2* __restrict__ cB,
                    const float2* __restrict__ W2){
  __shared__ float2 xin[16][20];
  __shared__ float2 Xf[20][16];
  __shared__ float2 Mx[20][16];
  __shared__ float2 twf[20], twi[20];
  int tid = threadIdx.x;
  if (tid < 20){
    float a = -6.283185307179586f*tid/20.0f;
    twf[tid] = make_float2(cosf(a), sinf(a));
    twi[tid] = make_float2(cosf(a), -sinf(a));
  }
  int bid = blockIdx.x;
  int b = bid/200, rem = bid%200;
  int ky = rem/10, kz = rem%10;
  const float2* src = cA + (size_t)((b*20+ky)*10+kz)*320;
  for (int t = tid; t < 320; t += 256){
    int x = t/16, i = t%16;
    xin[i][x] = src[t];
  }
  __syncthreads();
  for (int t = tid; t < 320; t += 256){
    int kx = t/16, i = t%16;
    float sr=0.0f, si=0.0f; int j=0;
    for (int x=0;x<20;++x){
      float2 v = xin[i][x]; float2 w = twf[j];
      sr += v.x*w.x - v.y*w.y; si += v.x*w.y + v.y*w.x;
      j += kx; if (j>=20) j-=20;
    }
    Xf[kx][i] = make_float2(sr,si);
  }
  __syncthreads();
  for (int t = tid; t < 320; t += 256){
    int kx = t/16, o = t%16;
    const float2* wp = W2 + ((size_t)(ky*20+kx)*10 + kz)*256 + o;
    float sr=0.0f, si=0.0f;
    #pragma unroll
    for (int i=0;i<16;++i){
      float2 a = Xf[kx][i];
      float2 w = wp[i*16];
      sr += a.x*w.x - a.y*w.y;
      si += a.x*w.y + a.y*w.x;
    }
    Mx[kx][o] = make_float2(sr,si);
  }
  __syncthreads();
  for (int t = tid; t < 320; t += 256){
    int x = t/16, o = t%16;
    float sr=0.0f, si=0.0f; int j=0;
    for (int kx=0;kx<20;++kx){
      float2 v = Mx[kx][o]; float2 w = twi[j];
      sr += v.x*w.x - v.y*w.y; si += v.x*w.y + v.y*w.x;
      j += x; if (j>=20) j-=20;
    }
    cB[((size_t)((b*20+x)*20+ky)*10+kz)*16 + o] = make_float2(sr,si);
  }
}

// stage C: y-inverse + z-inverse(real, irfft semantics), per (b, X, chan-group)
__global__ __launch_bounds__(256) void yzinv_k(const float2* __restrict__ cB, float* __restrict__ spec){
  __shared__ float2 ci[20][10][4];
  __shared__ float2 ty[20][10][4];
  __shared__ float2 twi[20];
  int tid = threadIdx.x;
  if (tid < 20){ float a = 6.283185307179586f*tid/20.0f; twi[tid] = make_float2(cosf(a), sinf(a)); }
  int bid = blockIdx.x;
  int b = bid/80, rem = bid%80;
  int X = rem>>2, cg = rem&3;
  const float2* src = cB + (size_t)(b*20+X)*200*16;
  for (int t = tid; t < 800; t += 256){
    int c = t&3, kz = (t>>2)%10, ky = t/40;
    ci[ky][kz][c] = src[(size_t)(ky*10+kz)*16 + cg*4+c];
  }
  __syncthreads();
  for (int t = tid; t < 800; t += 256){
    int c = t&3, kz = (t>>2)%10, y = t/40;
    float sr=0.0f, si=0.0f; int j=0;
    for (int ky=0;ky<20;++ky){
      float2 v = ci[ky][kz][c]; float2 w = twi[j];
      sr += v.x*w.x - v.y*w.y; si += v.x*w.y + v.y*w.x;
      j += y; if (j>=20) j-=20;
    }
    ty[y][kz][c] = make_float2(sr,si);
  }
  __syncthreads();
  float* dst = spec + (size_t)(b*20+X)*400*16 + cg*4;
  for (int t = tid; t < 1600; t += 256){
    int c = t&3, z = (t>>2)%20, y = t/80;
    float acc = ty[y][0][c].x;   // kz=0: w=1, Im ignored
    float a2 = 0.0f; int jj = 0;
    for (int kz=1; kz<10; ++kz){
      jj += z; if (jj>=20) jj-=20;
      float2 v = ty[y][kz][c]; float2 w = twi[jj];
      a2 += v.x*w.x - v.y*w.y;
    }
    acc += 2.0f*a2;
    dst[(size_t)(y*20+z)*16 + c] = acc * (1.0f/8000.0f);
  }
}

// fused FNO tail, 2-way k-split (bank-conflict-free)
__global__ __launch_bounds__(256) void ffn3_k(const float* __restrict__ spec, const float* __restrict__ h,
                     const float* __restrict__ pw, const float* __restrict__ ff1,
                     const float* __restrict__ ff2, float* __restrict__ hout){
  __shared__ float spw[256];
  __shared__ float sf1[1024];
  __shared__ float sf2[1024];
  __shared__ float h2s[128][17];
  __shared__ float red[2][128][17];
  int tid = threadIdx.x;
  spw[tid] = pw[tid];
  for (int t = tid; t < 1024; t += 256){ sf1[t]=ff1[t]; sf2[t]=ff2[t]; }
  int rl = tid >> 1, q = tid & 1;
  int m = blockIdx.x*128 + rl;
  const float* hr = h + (size_t)m*16;
  float hl[16];
  #pragma unroll
  for (int i=0;i<16;++i) hl[i] = hr[i];
  __syncthreads();
  const float* sp = spec + (size_t)m*16;
  #pragma unroll
  for (int c=0;c<8;++c){
    int o = q*8+c;
    float acc = sp[o];
    #pragma unroll
    for (int i=0;i<16;++i) acc += hl[i]*spw[i*16+o];
    h2s[rl][o] = geluf(acc);
  }
  __syncthreads();
  float h2l[16];
  #pragma unroll
  for (int i=0;i<16;++i) h2l[i] = h2s[rl][i];
  float part[16] = {};
  for (int kk=0;kk<32;++kk){
    int k = q*32+kk;
    float a0=0.0f, a1=0.0f;
    #pragma unroll
    for (int i=0;i<8;++i){ a0 += h2l[i]*sf1[i*64+k]; a1 += h2l[8+i]*sf1[(8+i)*64+k]; }
    float tk = geluf(a0+a1);
    #pragma unroll
    for (int o=0;o<16;++o) part[o] += tk*sf2[k*16+o];
  }
  #pragma unroll
  for (int o=0;o<16;++o) red[q][rl][o] = part[o];
  __syncthreads();
  #pragma unroll
  for (int c=0;c<8;++c){
    int o = q*8+c;
    hout[(size_t)m*16+o] = h2s[rl][o] + red[0][rl][o] + red[1][rl][o];
  }
}

// fused final projection, 2-way k-split
__global__ __launch_bounds__(256) void fctail3_k(const float* __restrict__ h, const float* __restrict__ fc1,
                        const float* __restrict__ fc2, float* __restrict__ outm){
  __shared__ float s1[2048];
  __shared__ float s2[2048];
  __shared__ float red[2][128][17];
  int tid = threadIdx.x;
  for (int t = tid; t < 2048; t += 256){ s1[t]=fc1[t]; s2[t]=fc2[t]; }
  int rl = tid >> 1, q = tid & 1;
  int m = blockIdx.x*128 + rl;
  const float* hr = h + (size_t)m*16;
  float hl[16];
  #pragma unroll
  for (int i=0;i<16;++i) hl[i] = hr[i];
  __syncthreads();
  float part[16] = {};
  for (int kk=0;kk<64;++kk){
    int k = q*64+kk;
    float a0=0.0f, a1=0.0f;
    #pragma unroll
    for (int i=0;i<8;++i){ a0 += hl[i]*s1[i*128+k]; a1 += hl[8+i]*s1[(8+i)*128+k]; }
    float tk = geluf(a0+a1);
    #pragma unroll
    for (int o=0;o<16;++o) part[o] += tk*s2[k*16+o];
  }
  #pragma unroll
  for (int o=0;o<16;++o) red[q][rl][o] = part[o];
  __syncthreads();
  #pragma unroll
  for (int c=0;c<8;++c){
    int o = q*8+c;
    outm[(size_t)m*16+o] = red[0][rl][o] + red[1][rl][o];
  }
}

// ---------------- m2a + final ----------------
__global__ void m2a_k(const float* __restrict__ mf2, const int* __restrict__ mdst,
                      const int* __restrict__ asrc, const float* __restrict__ sh2,
                      const float* __restrict__ Wt, const float* __restrict__ EL,
                      const float* __restrict__ T, float* __restrict__ af){
  int e = blockIdx.x*256 + threadIdx.x;
  if (e >= E2_) return;
  const float* xr = mf2 + (size_t)mdst[e]*16;
  const float* sr = sh2 + (size_t)e*9;
  float sh[9];
  #pragma unroll
  for (int s=0;s<9;++s) sh[s] = sr[s];
  float acc = 0.0f;
  #pragma unroll
  for (int f=0;f<16;++f) {
    float xv = xr[f];
    float dot = 0.0f;
    #pragma unroll
    for (int s=0;s<9;++s) dot += sh[s]*Wt[f*9+s];
    acc += xv*dot;
  }
  float rv = lerp_tab(T, EL[e], 1, 0);
  atomicAdd(&af[asrc[e]], acc*rv);
}

__global__ void bsum_k(const float* __restrict__ af, const int* __restrict__ batch,
                       float* __restrict__ out){
  int n = blockIdx.x*256 + threadIdx.x;
  if (n >= N_) return;
  atomicAdd(&out[batch[n]], af[n]);
}

} // namespace

extern "C" void kernel_launch(void* const* d_in, const int* in_sizes, int n_in,
                              void* d_out, int out_size, void* d_ws, size_t ws_size,
                              hipStream_t stream) {
  (void)in_sizes; (void)n_in; (void)out_size; (void)ws_size;
  const float* pos   = (const float*)d_in[0];
  const float* cell  = (const float*)d_in[1];
  const int*   an    = (const int*)d_in[2];
  const int*   batch = (const int*)d_in[3];
  const int*   esrc  = (const int*)d_in[4];
  const int*   edst  = (const int*)d_in[5];
  const int*   asrc  = (const int*)d_in[6];
  const int*   mdst  = (const int*)d_in[7];
  const float* emb   = (const float*)d_in[8];
  const float* g0_W  = (const float*)d_in[9];
  const float* g0_Wsc= (const float*)d_in[10];
  const float* g0_m1 = (const float*)d_in[11];
  const float* g0_m2 = (const float*)d_in[12];
  const float* g0_m3 = (const float*)d_in[13];
  const float* g12_W = (const float*)d_in[14];
  const float* g12_Wsc=(const float*)d_in[15];
  const float* g12_m1= (const float*)d_in[16];
  const float* g12_m2= (const float*)d_in[17];
  const float* g12_m3= (const float*)d_in[18];
  const float* a2m_W = (const float*)d_in[19];
  const float* a2m_m1= (const float*)d_in[20];
  const float* a2m_m2= (const float*)d_in[21];
  const float* a2m_m3= (const float*)d_in[22];
  const float* m2a_W = (const float*)d_in[23];
  const float* m2a_m1= (const float*)d_in[24];
  const float* m2a_m2= (const float*)d_in[25];
  const float* m2a_m3= (const float*)d_in[26];
  const float* fc0_W = (const float*)d_in[27];
  const float* fc0_b = (const float*)d_in[28];
  const float* sw_r  = (const float*)d_in[29];
  const float* sw_i  = (const float*)d_in[30];
  const float* pw    = (const float*)d_in[31];
  const float* ff1   = (const float*)d_in[32];
  const float* ff2   = (const float*)d_in[33];
  const float* fc1   = (const float*)d_in[34];
  const float* fc2   = (const float*)d_in[35];
  float* out = (float*)d_out;

  float* Wp = (float*)d_ws;
  size_t off = 0;
  auto alloc = [&](size_t n){ off = (off+3)&~(size_t)3; float* p = Wp + off; off += n; return p; };
  float* meshpos = alloc((size_t)M_*3);
  float* she   = alloc((size_t)E_*9);
  float* ELe   = alloc((size_t)E_);
  float* sh2   = alloc((size_t)E2_*9);
  float* EL2   = alloc((size_t)E2_);
  float* x16   = alloc((size_t)N_*16);
  float* xatom = alloc((size_t)N_*144);
  float* Yg    = alloc((size_t)N_*1296);         // per-atom Y
  float* mf    = alloc((size_t)M_*32);
  float* hbuf  = alloc((size_t)M_*16);
  float* htmp  = alloc((size_t)M_*16);
  float2* cA   = (float2*)alloc(1024000);
  float2* cB   = (float2*)alloc(1024000);
  float2* W2   = (float2*)alloc((size_t)3*2048000); // reordered spectral weights (3 layers)
  float* af    = alloc((size_t)N_);
  float* Es    = alloc((size_t)NT_*64);
  float* H1g   = alloc((size_t)5*NT_*128);
  float* H2g   = alloc((size_t)5*NT_*128);
  float* T0    = alloc((size_t)NT_*144);
  float* T1    = alloc((size_t)NT_*144);
  float* T2    = alloc((size_t)NT_*144);
  float* T3    = alloc((size_t)NT_*32);
  float* T4    = alloc((size_t)NT_*1);
  // bf16 buffers (ushort counts / 2, rounded up)
  unsigned short* Ah  = (unsigned short*)alloc((size_t)N_*160/2);
  unsigned short* Al  = (unsigned short*)alloc((size_t)N_*160/2);
  unsigned short* BTh = (unsigned short*)alloc((size_t)1296*160/2);
  unsigned short* BTl = (unsigned short*)alloc((size_t)1296*160/2);
  unsigned short* BWh = (unsigned short*)alloc((size_t)144*160/2);
  unsigned short* BWl = (unsigned short*)alloc((size_t)144*160/2);

  auto g1 = [](int n){ return dim3((unsigned)((n+255)/256)); };
  auto mg = [](int tiles){ return dim3((unsigned)((tiles+3)/4)); };  // 4 waves/block
  const int TM = N_/16; // 128 row tiles

  // zero accumulators
  zero_k<<<g1(8), 256, 0, stream>>>(out, 8);
  zero_k<<<g1(N_), 256, 0, stream>>>(af, N_);
  zero_k<<<g1(M_*32), 256, 0, stream>>>(mf, M_*32);

  // geometry
  meshpos_k<<<g1(M_), 256, 0, stream>>>(cell, meshpos);
  edge_geom2_k<<<g1(E_), 256, 0, stream>>>(pos, esrc, pos, edst, she, ELe, E_);
  edge_geom2_k<<<g1(E2_), 256, 0, stream>>>(meshpos, mdst, pos, asrc, sh2, EL2, E2_);
  gather_emb_k<<<g1(N_*16), 256, 0, stream>>>(emb, an, x16);

  // spectral weight reorder (LDS transpose, all 3 layers in one launch)
  wreorder2_k<<<dim3(400,3), 256, 0, stream>>>(sw_r, sw_i, W2);

  // ---- radial tables via 3 batched GEMMs ----
  {
    es_k<<<g1(NT_*64), 256, 0, stream>>>(Es);
    BG l1, l2, l3;
    const float* m1s[5] = {g0_m1, g12_m1, g12_m1+(size_t)64*128, a2m_m1, m2a_m1};
    const float* m2s[5] = {g0_m2, g12_m2, g12_m2+(size_t)128*128, a2m_m2, m2a_m2};
    const float* m3s[5] = {g0_m3, g12_m3, g12_m3+(size_t)128*144, a2m_m3, m2a_m3};
    float* Ts[5] = {T0, T1, T2, T3, T4};
    int NOs[5] = {144, 144, 144, 32, 1};
    for (int c = 0; c < 5; ++c) {
      l1.A[c] = Es;                      l1.B[c] = m1s[c]; l1.C[c] = H1g + (size_t)c*NT_*128; l1.Nc[c] = 128;
      l2.A[c] = H1g + (size_t)c*NT_*128; l2.B[c] = m2s[c]; l2.C[c] = H2g + (size_t)c*NT_*128; l2.Nc[c] = 128;
      l3.A[c] = H2g + (size_t)c*NT_*128; l3.B[c] = m3s[c]; l3.C[c] = Ts[c];                   l3.Nc[c] = NOs[c];
    }
    l1.K = 64; l2.K = 128; l3.K = 128;
    bgemm_k<1><<<dim3(2, NT_/64, 5), 256, 0, stream>>>(l1);
    bgemm_k<1><<<dim3(2, NT_/64, 5), 256, 0, stream>>>(l2);
    bgemm_k<0><<<dim3(3, NT_/64, 5), 256, 0, stream>>>(l3);
  }

  // ---- g0 (KP=32) ----
  convA_k<<<g1(N_*32), 256, 0, stream>>>(x16, Ah, Al, N_, 16, 32);
  wreshapeT_k<144><<<g1(9*144*32), 256, 0, stream>>>(g0_W, BTh, BTl, 16, 32);
  convT_k<<<g1(144*32), 256, 0, stream>>>(g0_Wsc, BWh, BWl, 16, 144, 32);
  mgemm_k<<<mg(TM*81), 256, 0, stream>>>(Ah, Al, BTh, BTl, Yg, N_, 32, 1296);
  mgemm_k<<<mg(TM*9),  256, 0, stream>>>(Ah, Al, BWh, BWl, xatom, N_, 32, 144);
  econtract_k<144><<<g1(E_*144), 256, 0, stream>>>(Yg, esrc, edst, she, ELe, T0, xatom, E_);

  // ---- g12 x2 (KP=160) ----
  for (int i = 0; i < 2; ++i) {
    normact_bf_k<<<g1(N_*16), 256, 0, stream>>>(xatom, Ah, Al);
    wreshapeT_k<144><<<g1(9*144*160), 256, 0, stream>>>(g12_W + (size_t)i*1296*144, BTh, BTl, 144, 160);
    convT_k<<<g1(144*160), 256, 0, stream>>>(g12_Wsc + (size_t)i*144*144, BWh, BWl, 144, 144, 160);
    mgemm_k<<<mg(TM*81), 256, 0, stream>>>(Ah, Al, BTh, BTl, Yg, N_, 160, 1296);
    mgemm_k<<<mg(TM*9),  256, 0, stream>>>(Ah, Al, BWh, BWl, xatom, N_, 160, 144);
    econtract_k<144><<<g1(E_*144), 256, 0, stream>>>(Yg, esrc, edst, she, ELe, (i==0)?T1:T2, xatom, E_);
  }

  // ---- a2m (KP=160) ----
  convA_k<<<g1(N_*160), 256, 0, stream>>>(xatom, Ah, Al, N_, 144, 160);
  wreshapeT_k<32><<<g1(9*32*160), 256, 0, stream>>>(a2m_W, BTh, BTl, 144, 160);
  mgemm_k<<<mg(TM*18), 256, 0, stream>>>(Ah, Al, BTh, BTl, Yg, N_, 160, 288);
  econtract_k<32><<<g1(E2_*32), 256, 0, stream>>>(Yg, asrc, mdst, sh2, EL2, T3, mf, E2_);

  // ---- FNO ----
  fc0_k<<<g1(M_*16), 256, 0, stream>>>(mf, fc0_W, fc0_b, hbuf);
  for (int l = 0; l < 3; ++l) {
    zyfwd_k<<<dim3(640), 256, 0, stream>>>(hbuf, cA);
    xmix_k<<<dim3(1600), 256, 0, stream>>>(cA, cB, W2 + (size_t)l*1024000);
    yzinv_k<<<dim3(640), 256, 0, stream>>>(cB, htmp);
    ffn3_k<<<dim3(500), 256, 0, stream>>>(htmp, hbuf, pw + (size_t)l*256,
                                          ff1 + (size_t)l*1024, ff2 + (size_t)l*1024, hbuf);
  }
  fctail3_k<<<dim3(500), 256, 0, stream>>>(hbuf, fc1, fc2, htmp);

  // ---- m2a + batch reduce ----
  m2a_k<<<g1(E2_), 256, 0, stream>>>(htmp, mdst, asrc, sh2, m2a_W, EL2, T4, af);
  bsum_k<<<g1(N_), 256, 0, stream>>>(af, batch, out);
}